// Round 3
// baseline (366.731 us; speedup 1.0000x reference)
//
#include <hip/hip_runtime.h>
#include <math.h>

#define N_CELLS 16384
#define HID 512
#define IND 512
#define KNB 15
#define NCOPY 64

// ---- workspace layout (bytes) ----
#define EMIS_OFF  128                                 // float[NCOPY][1024]: emission partials (re[512], im[512])
#define LAS_OFF   (EMIS_OFF + NCOPY*1024*4)           // int[N_CELLS]: lasing flags
#define CAV_OFF   (LAS_OFF + N_CELLS*4)               // float[1536]: cav_new_re[512], cav_new_im[512], cav_phase[512]
#define VPART_OFF (CAV_OFF + 1536*4)                  // float2[N_CELLS]: per-cell (sum_a, sum_a2) partials
#define ROT_OFF   (1<<20)                             // float2[N_CELLS*HID]: rotated states
#define NST_OFF   (ROT_OFF + (size_t)N_CELLS*HID*8)   // float2[N_CELLS*HID]: new_states (pre-lock)

// ---------------------------------------------------------------------------
// Kernel 1: pump = sigmoid(x . pump_W[i] + pump_b[i]); excited update; lasing
// One wave (64 lanes) per cell. NO global atomics (k_cav counts the flags).
__global__ __launch_bounds__(256) void k_pump(const float* __restrict__ x,
                                              const float* __restrict__ pW,
                                              const float* __restrict__ pb,
                                              const float* __restrict__ excited,
                                              int* __restrict__ lasing) {
    int gtid = blockIdx.x * 256 + threadIdx.x;
    int cell = gtid >> 6;
    int lane = gtid & 63;
    const float4* w4 = (const float4*)(pW + (size_t)cell * IND);
    const float4* x4 = (const float4*)x;
    float acc = 0.f;
#pragma unroll
    for (int t = 0; t < (IND / 4) / 64; ++t) {     // 2 iters
        float4 a = w4[lane + 64 * t];
        float4 b = x4[lane + 64 * t];
        acc += a.x * b.x + a.y * b.y + a.z * b.z + a.w * b.w;
    }
#pragma unroll
    for (int o = 32; o; o >>= 1) acc += __shfl_xor(acc, o, 64);
    if (lane == 0) {
        float p = 1.f / (1.f + expf(-(acc + pb[cell])));
        float e = excited[cell] * 0.95f + p * 0.05f;
        e = fminf(fmaxf(e, 0.f), 1.f);
        lasing[cell] = (e > 0.5f) ? 1 : 0;
    }
}

// ---------------------------------------------------------------------------
// Kernel 2: rotate states by exp(i * 0.1 * phase_vel). 4 elems/thread.
__global__ __launch_bounds__(256) void k_rot(const float* __restrict__ cr,
                                             const float* __restrict__ ci,
                                             const float* __restrict__ pv,
                                             float2* __restrict__ rot) {
    int i = blockIdx.x * 256 + threadIdx.x;        // over N*H/4
    const float4* cr4 = (const float4*)cr;
    const float4* ci4 = (const float4*)ci;
    const float4* pv4 = (const float4*)pv;
    float4 a = cr4[i], b = ci4[i], t = pv4[i];
    float s0, c0, s1, c1, s2, c2, s3, c3;
    __sincosf(0.1f * t.x, &s0, &c0);
    __sincosf(0.1f * t.y, &s1, &c1);
    __sincosf(0.1f * t.z, &s2, &c2);
    __sincosf(0.1f * t.w, &s3, &c3);
    float4 o0 = make_float4(a.x * c0 - b.x * s0, a.x * s0 + b.x * c0,
                            a.y * c1 - b.y * s1, a.y * s1 + b.y * c1);
    float4 o1 = make_float4(a.z * c2 - b.z * s2, a.z * s2 + b.z * c2,
                            a.w * c3 - b.w * s3, a.w * s3 + b.w * c3);
    float4* r4 = (float4*)rot;
    r4[2 * i]     = o0;
    r4[2 * i + 1] = o1;
}

// ---------------------------------------------------------------------------
// Kernel 3: neighbor coupling. Block = 512 threads = 4 cells x 128 threads;
// each thread owns 4 CONTIGUOUS channels -> every neighbor gather is
// 2x global_load_dwordx4 sharing ONE address computation.
// XCD swizzle: 4096 blocks; blk%8 = XCD (hw round-robin) -> each XCD owns a
// contiguous 2048-cell window, so low-bit hypercube neighbors hit its L2.
__global__ __launch_bounds__(512) void k_coup(const float2* __restrict__ rot,
                                              const int* __restrict__ nbrs,
                                              const int* __restrict__ lasing,
                                              float2* __restrict__ nst,
                                              float* __restrict__ emis) {
    __shared__ int nb[4 * KNB];
    __shared__ int sl[4];
    int blk = blockIdx.x;
    int logical = (blk & 7) * 512 + (blk >> 3);    // 4096 blocks -> XCD-contiguous
    int tid = threadIdx.x;
    if (tid < 4 * KNB) nb[tid] = nbrs[logical * 4 * KNB + tid];
    if (tid >= 64 && tid < 68) sl[tid - 64] = lasing[logical * 4 + (tid - 64)];
    __syncthreads();

    int cl = tid >> 7;                             // cell-in-block 0..3
    int c0 = (tid & 127) << 2;                     // channel base 0,4,..,508
    int cell = logical * 4 + cl;

    const float4* s4 = (const float4*)(rot + (size_t)cell * HID + c0);
    float4 sa = s4[0], sb = s4[1];
    float r0 = rsqrtf(sa.x * sa.x + sa.y * sa.y);
    float r1 = rsqrtf(sa.z * sa.z + sa.w * sa.w);
    float r2 = rsqrtf(sb.x * sb.x + sb.y * sb.y);
    float r3 = rsqrtf(sb.z * sb.z + sb.w * sb.w);

    float ar0 = 0.f, ai0 = 0.f, ar1 = 0.f, ai1 = 0.f;
    float ar2 = 0.f, ai2 = 0.f, ar3 = 0.f, ai3 = 0.f;
    const int* nbp = nb + cl * KNB;
#pragma unroll
    for (int t = 0; t < KNB; ++t) {
        const float4* q4 = (const float4*)(rot + (size_t)nbp[t] * HID + c0);
        float4 qa = q4[0], qb = q4[1];
        float d, qi, w;
        d = sa.x * qa.x + sa.y * qa.y; qi = rsqrtf(qa.x * qa.x + qa.y * qa.y);
        w = d * r0 * qi; ar0 = fmaf(w, qa.x, ar0); ai0 = fmaf(w, qa.y, ai0);
        d = sa.z * qa.z + sa.w * qa.w; qi = rsqrtf(qa.z * qa.z + qa.w * qa.w);
        w = d * r1 * qi; ar1 = fmaf(w, qa.z, ar1); ai1 = fmaf(w, qa.w, ai1);
        d = sb.x * qb.x + sb.y * qb.y; qi = rsqrtf(qb.x * qb.x + qb.y * qb.y);
        w = d * r2 * qi; ar2 = fmaf(w, qb.x, ar2); ai2 = fmaf(w, qb.y, ai2);
        d = sb.z * qb.z + sb.w * qb.w; qi = rsqrtf(qb.z * qb.z + qb.w * qb.w);
        w = d * r3 * qi; ar3 = fmaf(w, qb.z, ar3); ai3 = fmaf(w, qb.w, ai3);
    }
    // new = 0.7*s + (0.3*0.1/15) * sum
    float4 oa = make_float4(0.7f * sa.x + 0.002f * ar0, 0.7f * sa.y + 0.002f * ai0,
                            0.7f * sa.z + 0.002f * ar1, 0.7f * sa.w + 0.002f * ai1);
    float4 ob = make_float4(0.7f * sb.x + 0.002f * ar2, 0.7f * sb.y + 0.002f * ai2,
                            0.7f * sb.z + 0.002f * ar3, 0.7f * sb.w + 0.002f * ai3);
    float4* o4 = (float4*)(nst + (size_t)cell * HID + c0);
    o4[0] = oa;
    o4[1] = ob;
    if (sl[cl]) {
        float* em = emis + (size_t)(cell & (NCOPY - 1)) * 1024;
        atomicAdd(em + c0,           oa.x); atomicAdd(em + 512 + c0,     oa.y);
        atomicAdd(em + c0 + 1,       oa.z); atomicAdd(em + 512 + c0 + 1, oa.w);
        atomicAdd(em + c0 + 2,       ob.x); atomicAdd(em + 512 + c0 + 2, ob.y);
        atomicAdd(em + c0 + 3,       ob.z); atomicAdd(em + 512 + c0 + 3, ob.w);
    }
}

// ---------------------------------------------------------------------------
// Kernel 4: count lasing flags; reduce emission copies; cavity_new;
// cavity_phase (OLD cavity). One block, 512 threads.
__global__ __launch_bounds__(512) void k_cav(const float* __restrict__ emis,
                                             const int* __restrict__ lasv,
                                             const float* __restrict__ cavr,
                                             const float* __restrict__ cavi,
                                             float* __restrict__ cav) {
    __shared__ int cnt[8];
    __shared__ int snl;
    int c = threadIdx.x;
    int wid = c >> 6, lane = c & 63;
    int n = 0;
#pragma unroll
    for (int k = 0; k < N_CELLS / 512; ++k) n += lasv[c + 512 * k];  // 32 iters
#pragma unroll
    for (int o = 32; o; o >>= 1) n += __shfl_xor(n, o, 64);
    if (lane == 0) cnt[wid] = n;
    __syncthreads();
    if (c == 0) { int t = 0; for (int k = 0; k < 8; ++k) t += cnt[k]; snl = t; }
    __syncthreads();
    int nl = snl;

    float er = 0.f, ei = 0.f;
    for (int k = 0; k < NCOPY; ++k) {
        er += emis[k * 1024 + c];
        ei += emis[k * 1024 + 512 + c];
    }
    float cr = cavr[c], ci = cavi[c];
    float nr, ni;
    if (nl > 0) {
        float inv = 1.f / (float)(nl > 1 ? nl : 1);
        nr = 0.8f * cr + 0.2f * er * inv;
        ni = 0.8f * ci + 0.2f * ei * inv;
    } else {
        nr = cr;
        ni = ci;
    }
    cav[c] = nr;
    cav[512 + c] = ni;
    cav[1024 + c] = atan2f(ci, cr);                // old cavity phase
}

// ---------------------------------------------------------------------------
// Kernel 5: pred = [cav_new.re, cav_new.im] @ dec_W.T + dec_b. Wave per row.
__global__ __launch_bounds__(512) void k_pred(const float* __restrict__ cav,
                                              const float* __restrict__ dW,
                                              const float* __restrict__ db,
                                              float* __restrict__ out) {
    int gtid = blockIdx.x * 512 + threadIdx.x;
    int j = gtid >> 6;                             // 512 waves -> 512 outputs
    int lane = gtid & 63;
    const float4* w4 = (const float4*)(dW + (size_t)j * (2 * HID));
    const float4* o4 = (const float4*)cav;         // first 1024 floats = out_real
    float acc = 0.f;
#pragma unroll
    for (int t = 0; t < (2 * HID / 4) / 64; ++t) { // 4 iters
        float4 a = w4[lane + 64 * t];
        float4 b = o4[lane + 64 * t];
        acc += a.x * b.x + a.y * b.y + a.z * b.z + a.w * b.w;
    }
#pragma unroll
    for (int o = 32; o; o >>= 1) acc += __shfl_xor(acc, o, 64);
    if (lane == 0) out[j] = acc + db[j];
}

// ---------------------------------------------------------------------------
// Kernel 6: phase-lock lasing cells, add cavity feedback, row-max renorm,
// write per-cell (sum_a, sum_a2) partials. Block per cell. NO global atomics.
__global__ __launch_bounds__(512) void k_fin(const float2* __restrict__ nst,
                                             const int* __restrict__ lasing,
                                             const float* __restrict__ cav,
                                             float2* __restrict__ vpart) {
    __shared__ float sred[8];
    __shared__ float sbc;
    int cell = blockIdx.x;
    int c = threadIdx.x;
    int wid = c >> 6, lane = c & 63;
    int las = lasing[cell];

    float2 v = nst[(size_t)cell * HID + c];
    if (las) {
        float r = sqrtf(v.x * v.x + v.y * v.y);
        float ang = atan2f(v.y, v.x);
        float locked = 0.3f * cav[1024 + c] + 0.7f * ang;
        float sn, cs;
        __sincosf(locked, &sn, &cs);
        v = make_float2(r * cs, r * sn);
    }
    v.x += 0.05f * cav[c];
    v.y += 0.05f * cav[512 + c];
    float amp = sqrtf(v.x * v.x + v.y * v.y);

    // block max
    float m = amp;
#pragma unroll
    for (int o = 32; o; o >>= 1) m = fmaxf(m, __shfl_xor(m, o, 64));
    if (lane == 0) sred[wid] = m;
    __syncthreads();
    if (c == 0) {
        float mm = sred[0];
        for (int k = 1; k < 8; ++k) mm = fmaxf(mm, sred[k]);
        sbc = mm;
    }
    __syncthreads();
    float a = amp / (sbc + 1e-8f);

    // block sums of a and a^2
    float s1 = a, s2 = a * a;
#pragma unroll
    for (int o = 32; o; o >>= 1) { s1 += __shfl_xor(s1, o, 64); s2 += __shfl_xor(s2, o, 64); }
    __shared__ float w1[8], w2[8];
    if (lane == 0) { w1[wid] = s1; w2[wid] = s2; }
    __syncthreads();
    if (c == 0) {
        float t1 = 0.f, t2 = 0.f;
        for (int k = 0; k < 8; ++k) { t1 += w1[k]; t2 += w2[k]; }
        vpart[cell] = make_float2(t1, t2);         // contention-free store
    }
}

// ---------------------------------------------------------------------------
// Kernel 7: reduce per-cell partials (double accum); tension = E[a^2]-E[a]^2
__global__ __launch_bounds__(1024) void k_var(const float2* __restrict__ vpart,
                                              float* __restrict__ out) {
    __shared__ double l1[16], l2[16];
    int c = threadIdx.x;
    int wid = c >> 6, lane = c & 63;
    double s1 = 0.0, s2 = 0.0;
#pragma unroll
    for (int t = 0; t < N_CELLS / 1024; ++t) {     // 16 iters
        float2 p = vpart[c + 1024 * t];
        s1 += (double)p.x;
        s2 += (double)p.y;
    }
#pragma unroll
    for (int o = 32; o; o >>= 1) { s1 += __shfl_xor(s1, o, 64); s2 += __shfl_xor(s2, o, 64); }
    if (lane == 0) { l1[wid] = s1; l2[wid] = s2; }
    __syncthreads();
    if (c == 0) {
        double t1 = 0.0, t2 = 0.0;
        for (int k = 0; k < 16; ++k) { t1 += l1[k]; t2 += l2[k]; }
        double n = (double)N_CELLS * (double)HID;
        double mean = t1 / n;
        out[IND] = (float)(t2 / n - mean * mean);
    }
}

// ---------------------------------------------------------------------------
extern "C" void kernel_launch(void* const* d_in, const int* in_sizes, int n_in,
                              void* d_out, int out_size, void* d_ws, size_t ws_size,
                              hipStream_t stream) {
    const float* x       = (const float*)d_in[0];
    const float* pump_W  = (const float*)d_in[1];
    const float* pump_b  = (const float*)d_in[2];
    const float* dec_W   = (const float*)d_in[3];
    const float* dec_b   = (const float*)d_in[4];
    const float* cs_re   = (const float*)d_in[5];
    const float* cs_im   = (const float*)d_in[6];
    const float* excited = (const float*)d_in[7];
    const float* pvel    = (const float*)d_in[8];
    const float* cav_re  = (const float*)d_in[9];
    const float* cav_im  = (const float*)d_in[10];
    const int*   nbrs    = (const int*)d_in[11];

    float* out = (float*)d_out;
    char* ws = (char*)d_ws;
    float*  emis  = (float*)(ws + EMIS_OFF);
    int*    lasv  = (int*)(ws + LAS_OFF);
    float*  cav   = (float*)(ws + CAV_OFF);
    float2* vpart = (float2*)(ws + VPART_OFF);
    float2* rot   = (float2*)(ws + ROT_OFF);
    float2* nst   = (float2*)(ws + NST_OFF);

    // zero emission accumulators (ws is poisoned 0xAA before every launch)
    hipMemsetAsync(ws, 0, EMIS_OFF + NCOPY * 1024 * 4, stream);

    k_pump<<<N_CELLS / 4, 256, 0, stream>>>(x, pump_W, pump_b, excited, lasv);
    k_rot<<<(N_CELLS * HID / 4) / 256, 256, 0, stream>>>(cs_re, cs_im, pvel, rot);
    k_coup<<<N_CELLS / 4, 512, 0, stream>>>(rot, nbrs, lasv, nst, emis);
    k_cav<<<1, 512, 0, stream>>>(emis, lasv, cav_re, cav_im, cav);
    k_pred<<<64, 512, 0, stream>>>(cav, dec_W, dec_b, out);
    k_fin<<<N_CELLS, 512, 0, stream>>>(nst, lasv, cav, vpart);
    k_var<<<1, 1024, 0, stream>>>(vpart, out);
}

// Round 4
// 307.887 us; speedup vs baseline: 1.1911x; 1.1911x over previous
//
#include <hip/hip_runtime.h>
#include <math.h>

#define N_CELLS 16384
#define HID 512
#define IND 512
#define KNB 15
#define NCOPY 64

#define ROT_BLOCKS  8192    // N*H/4 elems / 256 threads
#define PUMP_BLOCKS 4096    // 4 cells per block (wave per cell)
#define ZERO_BLOCKS 64      // 64*256 float4 = 65536 floats (emis)

// ---- workspace layout (bytes) ----
#define EMIS_OFF  128                                 // float[NCOPY][1024]: emission partials (re[512], im[512])
#define LAS_OFF   (EMIS_OFF + NCOPY*1024*4)           // int[N_CELLS]: lasing flags
#define CAV_OFF   (LAS_OFF + N_CELLS*4)               // float[1536]: cav_new_re, cav_new_im, cav_phase
#define VPART_OFF (CAV_OFF + 1536*4)                  // float2[N_CELLS]: per-cell (sum_a, sum_a2) partials
#define ROT_OFF   (1<<20)                             // float2[N_CELLS*HID]: rotated states
#define NST_OFF   (ROT_OFF + (size_t)N_CELLS*HID*8)   // float2[N_CELLS*HID]: new_states (pre-lock)

// ---------------------------------------------------------------------------
// Kernel A (fused front): phase rotation + pump/lasing + emis zeroing.
// All three roles are independent and all precede k_coup.
__global__ __launch_bounds__(256) void k_front(const float* __restrict__ cr,
                                               const float* __restrict__ ci,
                                               const float* __restrict__ pv,
                                               float2* __restrict__ rot,
                                               const float* __restrict__ x,
                                               const float* __restrict__ pW,
                                               const float* __restrict__ pb,
                                               const float* __restrict__ excited,
                                               int* __restrict__ lasing,
                                               float* __restrict__ emis) {
    int b = blockIdx.x;
    int tid = threadIdx.x;
    if (b < ROT_BLOCKS) {
        // ---- rotate states by exp(i * 0.1 * phase_vel), 4 elems/thread ----
        int i = b * 256 + tid;
        const float4* cr4 = (const float4*)cr;
        const float4* ci4 = (const float4*)ci;
        const float4* pv4 = (const float4*)pv;
        float4 a = cr4[i], bb = ci4[i], t = pv4[i];
        float s0, c0, s1, c1, s2, c2, s3, c3;
        __sincosf(0.1f * t.x, &s0, &c0);
        __sincosf(0.1f * t.y, &s1, &c1);
        __sincosf(0.1f * t.z, &s2, &c2);
        __sincosf(0.1f * t.w, &s3, &c3);
        float4 o0 = make_float4(a.x * c0 - bb.x * s0, a.x * s0 + bb.x * c0,
                                a.y * c1 - bb.y * s1, a.y * s1 + bb.y * c1);
        float4 o1 = make_float4(a.z * c2 - bb.z * s2, a.z * s2 + bb.z * c2,
                                a.w * c3 - bb.w * s3, a.w * s3 + bb.w * c3);
        float4* r4 = (float4*)rot;
        r4[2 * i]     = o0;
        r4[2 * i + 1] = o1;
    } else if (b < ROT_BLOCKS + PUMP_BLOCKS) {
        // ---- pump = sigmoid(x . pump_W[cell] + pb); lasing flag. Wave/cell ----
        int gtid = (b - ROT_BLOCKS) * 256 + tid;
        int cell = gtid >> 6;
        int lane = gtid & 63;
        const float4* w4 = (const float4*)(pW + (size_t)cell * IND);
        const float4* x4 = (const float4*)x;
        float acc = 0.f;
#pragma unroll
        for (int t = 0; t < (IND / 4) / 64; ++t) {   // 2 iters
            float4 a = w4[lane + 64 * t];
            float4 bx = x4[lane + 64 * t];
            acc += a.x * bx.x + a.y * bx.y + a.z * bx.z + a.w * bx.w;
        }
#pragma unroll
        for (int o = 32; o; o >>= 1) acc += __shfl_xor(acc, o, 64);
        if (lane == 0) {
            float p = 1.f / (1.f + expf(-(acc + pb[cell])));
            float e = excited[cell] * 0.95f + p * 0.05f;
            e = fminf(fmaxf(e, 0.f), 1.f);
            lasing[cell] = (e > 0.5f) ? 1 : 0;
        }
    } else {
        // ---- zero emission accumulators ----
        int idx = (b - ROT_BLOCKS - PUMP_BLOCKS) * 256 + tid;
        ((float4*)emis)[idx] = make_float4(0.f, 0.f, 0.f, 0.f);
    }
}

// ---------------------------------------------------------------------------
// Kernel 3: neighbor coupling. Block = 1 cell (natural dispatch order -> L2
// temporal locality; round-3 swizzle raised FETCH 267->421 MB, do NOT swizzle).
// 256 threads, 2 channels/thread -> one dwordx4 per neighbor gather.
__global__ __launch_bounds__(256) void k_coup(const float2* __restrict__ rot,
                                              const int* __restrict__ nbrs,
                                              const int* __restrict__ lasing,
                                              float2* __restrict__ nst,
                                              float* __restrict__ emis) {
    __shared__ int nb[KNB];
    __shared__ int las;
    int cell = blockIdx.x;
    int tid = threadIdx.x;
    if (tid < KNB) nb[tid] = nbrs[cell * KNB + tid];
    if (tid == KNB) las = lasing[cell];
    __syncthreads();

    const float4* s4 = (const float4*)(rot + (size_t)cell * HID) + tid;
    float4 sa = *s4;
    float r0 = rsqrtf(sa.x * sa.x + sa.y * sa.y);
    float r1 = rsqrtf(sa.z * sa.z + sa.w * sa.w);

    float ar0 = 0.f, ai0 = 0.f, ar1 = 0.f, ai1 = 0.f;
#pragma unroll
    for (int t = 0; t < KNB; ++t) {
        const float4* q4 = (const float4*)(rot + (size_t)nb[t] * HID) + tid;
        float4 qa = *q4;
        float d, qi, w;
        d = sa.x * qa.x + sa.y * qa.y; qi = rsqrtf(qa.x * qa.x + qa.y * qa.y);
        w = d * r0 * qi; ar0 = fmaf(w, qa.x, ar0); ai0 = fmaf(w, qa.y, ai0);
        d = sa.z * qa.z + sa.w * qa.w; qi = rsqrtf(qa.z * qa.z + qa.w * qa.w);
        w = d * r1 * qi; ar1 = fmaf(w, qa.z, ar1); ai1 = fmaf(w, qa.w, ai1);
    }
    // new = 0.7*s + (0.3*0.1/15) * sum
    float4 oa = make_float4(0.7f * sa.x + 0.002f * ar0, 0.7f * sa.y + 0.002f * ai0,
                            0.7f * sa.z + 0.002f * ar1, 0.7f * sa.w + 0.002f * ai1);
    ((float4*)(nst + (size_t)cell * HID))[tid] = oa;
    if (las) {
        int c0 = tid << 1;
        float* em = emis + (size_t)(cell & (NCOPY - 1)) * 1024;
        atomicAdd(em + c0,     oa.x); atomicAdd(em + 512 + c0,     oa.y);
        atomicAdd(em + c0 + 1, oa.z); atomicAdd(em + 512 + c0 + 1, oa.w);
    }
}

// ---------------------------------------------------------------------------
// Kernel 4: count lasing flags; reduce emission copies; cavity_new;
// cavity_phase (OLD cavity). One block, 512 threads.
__global__ __launch_bounds__(512) void k_cav(const float* __restrict__ emis,
                                             const int* __restrict__ lasv,
                                             const float* __restrict__ cavr,
                                             const float* __restrict__ cavi,
                                             float* __restrict__ cav) {
    __shared__ int cnt[8];
    __shared__ int snl;
    int c = threadIdx.x;
    int wid = c >> 6, lane = c & 63;
    const int4* l4 = (const int4*)lasv;
    int n = 0;
#pragma unroll
    for (int k = 0; k < N_CELLS / 4 / 512; ++k) {  // 8 iters of int4
        int4 v = l4[c + 512 * k];
        n += v.x + v.y + v.z + v.w;
    }
#pragma unroll
    for (int o = 32; o; o >>= 1) n += __shfl_xor(n, o, 64);
    if (lane == 0) cnt[wid] = n;
    __syncthreads();
    if (c == 0) { int t = 0; for (int k = 0; k < 8; ++k) t += cnt[k]; snl = t; }
    __syncthreads();
    int nl = snl;

    float er = 0.f, ei = 0.f;
#pragma unroll 8
    for (int k = 0; k < NCOPY; ++k) {
        er += emis[k * 1024 + c];
        ei += emis[k * 1024 + 512 + c];
    }
    float cr = cavr[c], ci = cavi[c];
    float nr, ni;
    if (nl > 0) {
        float inv = 1.f / (float)(nl > 1 ? nl : 1);
        nr = 0.8f * cr + 0.2f * er * inv;
        ni = 0.8f * ci + 0.2f * ei * inv;
    } else {
        nr = cr;
        ni = ci;
    }
    cav[c] = nr;
    cav[512 + c] = ni;
    cav[1024 + c] = atan2f(ci, cr);                // old cavity phase
}

// ---------------------------------------------------------------------------
// Kernel 5: pred = [cav_new.re, cav_new.im] @ dec_W.T + dec_b. Wave per row.
__global__ __launch_bounds__(512) void k_pred(const float* __restrict__ cav,
                                              const float* __restrict__ dW,
                                              const float* __restrict__ db,
                                              float* __restrict__ out) {
    int gtid = blockIdx.x * 512 + threadIdx.x;
    int j = gtid >> 6;                             // 512 waves -> 512 outputs
    int lane = gtid & 63;
    const float4* w4 = (const float4*)(dW + (size_t)j * (2 * HID));
    const float4* o4 = (const float4*)cav;         // first 1024 floats = out_real
    float acc = 0.f;
#pragma unroll
    for (int t = 0; t < (2 * HID / 4) / 64; ++t) { // 4 iters
        float4 a = w4[lane + 64 * t];
        float4 b = o4[lane + 64 * t];
        acc += a.x * b.x + a.y * b.y + a.z * b.z + a.w * b.w;
    }
#pragma unroll
    for (int o = 32; o; o >>= 1) acc += __shfl_xor(acc, o, 64);
    if (lane == 0) out[j] = acc + db[j];
}

// ---------------------------------------------------------------------------
// Kernel 6: phase-lock lasing cells, add cavity feedback, row-max renorm,
// write per-cell (sum_a, sum_a2) partials. Block per cell. NO global atomics.
__global__ __launch_bounds__(512) void k_fin(const float2* __restrict__ nst,
                                             const int* __restrict__ lasing,
                                             const float* __restrict__ cav,
                                             float2* __restrict__ vpart) {
    __shared__ float sred[8];
    __shared__ float sbc;
    int cell = blockIdx.x;
    int c = threadIdx.x;
    int wid = c >> 6, lane = c & 63;
    int las = lasing[cell];

    float2 v = nst[(size_t)cell * HID + c];
    if (las) {
        float r = sqrtf(v.x * v.x + v.y * v.y);
        float ang = atan2f(v.y, v.x);
        float locked = 0.3f * cav[1024 + c] + 0.7f * ang;
        float sn, cs;
        __sincosf(locked, &sn, &cs);
        v = make_float2(r * cs, r * sn);
    }
    v.x += 0.05f * cav[c];
    v.y += 0.05f * cav[512 + c];
    float amp = sqrtf(v.x * v.x + v.y * v.y);

    // block max
    float m = amp;
#pragma unroll
    for (int o = 32; o; o >>= 1) m = fmaxf(m, __shfl_xor(m, o, 64));
    if (lane == 0) sred[wid] = m;
    __syncthreads();
    if (c == 0) {
        float mm = sred[0];
        for (int k = 1; k < 8; ++k) mm = fmaxf(mm, sred[k]);
        sbc = mm;
    }
    __syncthreads();
    float a = amp / (sbc + 1e-8f);

    // block sums of a and a^2
    float s1 = a, s2 = a * a;
#pragma unroll
    for (int o = 32; o; o >>= 1) { s1 += __shfl_xor(s1, o, 64); s2 += __shfl_xor(s2, o, 64); }
    __shared__ float w1[8], w2[8];
    if (lane == 0) { w1[wid] = s1; w2[wid] = s2; }
    __syncthreads();
    if (c == 0) {
        float t1 = 0.f, t2 = 0.f;
        for (int k = 0; k < 8; ++k) { t1 += w1[k]; t2 += w2[k]; }
        vpart[cell] = make_float2(t1, t2);         // contention-free store
    }
}

// ---------------------------------------------------------------------------
// Kernel 7: reduce per-cell partials (double accum); tension = E[a^2]-E[a]^2
__global__ __launch_bounds__(1024) void k_var(const float2* __restrict__ vpart,
                                              float* __restrict__ out) {
    __shared__ double l1[16], l2[16];
    int c = threadIdx.x;
    int wid = c >> 6, lane = c & 63;
    double s1 = 0.0, s2 = 0.0;
#pragma unroll
    for (int t = 0; t < N_CELLS / 1024; ++t) {     // 16 iters
        float2 p = vpart[c + 1024 * t];
        s1 += (double)p.x;
        s2 += (double)p.y;
    }
#pragma unroll
    for (int o = 32; o; o >>= 1) { s1 += __shfl_xor(s1, o, 64); s2 += __shfl_xor(s2, o, 64); }
    if (lane == 0) { l1[wid] = s1; l2[wid] = s2; }
    __syncthreads();
    if (c == 0) {
        double t1 = 0.0, t2 = 0.0;
        for (int k = 0; k < 16; ++k) { t1 += l1[k]; t2 += l2[k]; }
        double n = (double)N_CELLS * (double)HID;
        double mean = t1 / n;
        out[IND] = (float)(t2 / n - mean * mean);
    }
}

// ---------------------------------------------------------------------------
extern "C" void kernel_launch(void* const* d_in, const int* in_sizes, int n_in,
                              void* d_out, int out_size, void* d_ws, size_t ws_size,
                              hipStream_t stream) {
    const float* x       = (const float*)d_in[0];
    const float* pump_W  = (const float*)d_in[1];
    const float* pump_b  = (const float*)d_in[2];
    const float* dec_W   = (const float*)d_in[3];
    const float* dec_b   = (const float*)d_in[4];
    const float* cs_re   = (const float*)d_in[5];
    const float* cs_im   = (const float*)d_in[6];
    const float* excited = (const float*)d_in[7];
    const float* pvel    = (const float*)d_in[8];
    const float* cav_re  = (const float*)d_in[9];
    const float* cav_im  = (const float*)d_in[10];
    const int*   nbrs    = (const int*)d_in[11];

    float* out = (float*)d_out;
    char* ws = (char*)d_ws;
    float*  emis  = (float*)(ws + EMIS_OFF);
    int*    lasv  = (int*)(ws + LAS_OFF);
    float*  cav   = (float*)(ws + CAV_OFF);
    float2* vpart = (float2*)(ws + VPART_OFF);
    float2* rot   = (float2*)(ws + ROT_OFF);
    float2* nst   = (float2*)(ws + NST_OFF);

    k_front<<<ROT_BLOCKS + PUMP_BLOCKS + ZERO_BLOCKS, 256, 0, stream>>>(
        cs_re, cs_im, pvel, rot, x, pump_W, pump_b, excited, lasv, emis);
    k_coup<<<N_CELLS, 256, 0, stream>>>(rot, nbrs, lasv, nst, emis);
    k_cav<<<1, 512, 0, stream>>>(emis, lasv, cav_re, cav_im, cav);
    k_pred<<<64, 512, 0, stream>>>(cav, dec_W, dec_b, out);
    k_fin<<<N_CELLS, 512, 0, stream>>>(nst, lasv, cav, vpart);
    k_var<<<1, 1024, 0, stream>>>(vpart, out);
}

// Round 5
// 268.352 us; speedup vs baseline: 1.3666x; 1.1473x over previous
//
#include <hip/hip_runtime.h>
#include <hip/hip_fp16.h>
#include <math.h>

#define N_CELLS 16384
#define HID 512
#define IND 512
#define KNB 15
#define NCOPY 64

#define ROT_BLOCKS  8192    // N*H/4 elems / 256 threads
#define PUMP_BLOCKS 4096    // 4 cells per block (wave per cell)
#define ZERO_BLOCKS 64      // 64*256 float4 = 65536 floats (emis)

// ---- workspace layout (bytes) ----
#define EMIS_OFF  128                                 // float[NCOPY][1024]: emission partials (re[512], im[512])
#define LAS_OFF   (EMIS_OFF + NCOPY*1024*4)           // int[N_CELLS]: lasing flags
#define CAV_OFF   (LAS_OFF + N_CELLS*4)               // float[1536]: cav_new_re, cav_new_im, cav_phase
#define VPART_OFF (CAV_OFF + 1536*4)                  // float2[N_CELLS]: per-cell (sum_a, sum_a2) partials
#define ROT_OFF   (1<<20)                             // half2[N_CELLS*HID]: rotated states (fp16)
#define NST_OFF   (ROT_OFF + (size_t)N_CELLS*HID*4)   // half2[N_CELLS*HID]: new_states (fp16, pre-lock)

__device__ inline __half2 f2h2(float f) { union { float f; __half2 h; } u; u.f = f; return u.h; }
__device__ inline float   h22f(__half2 h) { union { float f; __half2 h; } u; u.h = h; return u.f; }

// ---------------------------------------------------------------------------
// Kernel A (fused front): phase rotation (fp16 out) + pump/lasing + emis zero.
__global__ __launch_bounds__(256) void k_front(const float* __restrict__ cr,
                                               const float* __restrict__ ci,
                                               const float* __restrict__ pv,
                                               __half2* __restrict__ rot,
                                               const float* __restrict__ x,
                                               const float* __restrict__ pW,
                                               const float* __restrict__ pb,
                                               const float* __restrict__ excited,
                                               int* __restrict__ lasing,
                                               float* __restrict__ emis) {
    int b = blockIdx.x;
    int tid = threadIdx.x;
    if (b < ROT_BLOCKS) {
        // ---- rotate states by exp(i * 0.1 * phase_vel), 4 elems/thread ----
        int i = b * 256 + tid;
        const float4* cr4 = (const float4*)cr;
        const float4* ci4 = (const float4*)ci;
        const float4* pv4 = (const float4*)pv;
        float4 a = cr4[i], bb = ci4[i], t = pv4[i];
        float s0, c0, s1, c1, s2, c2, s3, c3;
        __sincosf(0.1f * t.x, &s0, &c0);
        __sincosf(0.1f * t.y, &s1, &c1);
        __sincosf(0.1f * t.z, &s2, &c2);
        __sincosf(0.1f * t.w, &s3, &c3);
        // (re,im) per channel, packed to half2, 4 channels -> one float4 store
        __half2 p0 = __floats2half2_rn(a.x * c0 - bb.x * s0, a.x * s0 + bb.x * c0);
        __half2 p1 = __floats2half2_rn(a.y * c1 - bb.y * s1, a.y * s1 + bb.y * c1);
        __half2 p2 = __floats2half2_rn(a.z * c2 - bb.z * s2, a.z * s2 + bb.z * c2);
        __half2 p3 = __floats2half2_rn(a.w * c3 - bb.w * s3, a.w * s3 + bb.w * c3);
        ((float4*)rot)[i] = make_float4(h22f(p0), h22f(p1), h22f(p2), h22f(p3));
    } else if (b < ROT_BLOCKS + PUMP_BLOCKS) {
        // ---- pump = sigmoid(x . pump_W[cell] + pb); lasing flag. Wave/cell ----
        int gtid = (b - ROT_BLOCKS) * 256 + tid;
        int cell = gtid >> 6;
        int lane = gtid & 63;
        const float4* w4 = (const float4*)(pW + (size_t)cell * IND);
        const float4* x4 = (const float4*)x;
        float acc = 0.f;
#pragma unroll
        for (int t = 0; t < (IND / 4) / 64; ++t) {   // 2 iters
            float4 a = w4[lane + 64 * t];
            float4 bx = x4[lane + 64 * t];
            acc += a.x * bx.x + a.y * bx.y + a.z * bx.z + a.w * bx.w;
        }
#pragma unroll
        for (int o = 32; o; o >>= 1) acc += __shfl_xor(acc, o, 64);
        if (lane == 0) {
            float p = 1.f / (1.f + expf(-(acc + pb[cell])));
            float e = excited[cell] * 0.95f + p * 0.05f;
            e = fminf(fmaxf(e, 0.f), 1.f);
            lasing[cell] = (e > 0.5f) ? 1 : 0;
        }
    } else {
        // ---- zero emission accumulators ----
        int idx = (b - ROT_BLOCKS - PUMP_BLOCKS) * 256 + tid;
        ((float4*)emis)[idx] = make_float4(0.f, 0.f, 0.f, 0.f);
    }
}

// ---------------------------------------------------------------------------
// Kernel 3: neighbor coupling, fp16 states, packed-half inner loop.
// Block = 1 cell, natural dispatch order (round-3 lesson: do NOT swizzle).
// 256 threads, 2 channels/thread; per gather: one 8B load (2 half2).
// w*q = r_s * (d * r_q) * q  -- r_s factored into the epilogue.
__global__ __launch_bounds__(256) void k_coup(const __half2* __restrict__ rot,
                                              const int* __restrict__ nbrs,
                                              const int* __restrict__ lasing,
                                              __half2* __restrict__ nst,
                                              float* __restrict__ emis) {
    __shared__ int nb[KNB];
    __shared__ int las;
    int cell = blockIdx.x;
    int tid = threadIdx.x;
    if (tid < KNB) nb[tid] = nbrs[cell * KNB + tid];
    if (tid == KNB) las = lasing[cell];
    __syncthreads();

    const float2* rot2 = (const float2*)rot;       // 256 float2 per row
    float2 raw = rot2[(size_t)cell * (HID / 2) + tid];
    __half2 sa = f2h2(raw.x), sb = f2h2(raw.y);    // (re0,im0),(re1,im1)
    __half2 sre = __halves2half2(__low2half(sa), __low2half(sb));
    __half2 sim = __halves2half2(__high2half(sa), __high2half(sb));
    float s0x = __low2float(sa), s0y = __high2float(sa);
    float s1x = __low2float(sb), s1y = __high2float(sb);
    float r0 = rsqrtf(s0x * s0x + s0y * s0y);
    float r1 = rsqrtf(s1x * s1x + s1y * s1y);

    __half2 are = __float2half2_rn(0.f), aim = __float2half2_rn(0.f);
#pragma unroll
    for (int t = 0; t < KNB; ++t) {
        float2 qraw = rot2[(size_t)nb[t] * (HID / 2) + tid];
        __half2 qa = f2h2(qraw.x), qb = f2h2(qraw.y);
        __half2 qre = __halves2half2(__low2half(qa), __low2half(qb));
        __half2 qim = __halves2half2(__high2half(qa), __high2half(qb));
        __half2 d  = __hfma2(sim, qim, __hmul2(sre, qre));   // s.q per channel
        __half2 qn = __hfma2(qim, qim, __hmul2(qre, qre));   // |q|^2
        __half2 t2 = __hmul2(d, h2rsqrt(qn));                // d * r_q
        are = __hfma2(t2, qre, are);
        aim = __hfma2(t2, qim, aim);
    }
    float ar0 = __low2float(are), ar1 = __high2float(are);
    float ai0 = __low2float(aim), ai1 = __high2float(aim);
    // new = 0.7*s + (0.3*0.1/15) * r_s * sum
    float k0 = 0.002f * r0, k1 = 0.002f * r1;
    float nr0 = 0.7f * s0x + k0 * ar0, ni0 = 0.7f * s0y + k0 * ai0;
    float nr1 = 0.7f * s1x + k1 * ar1, ni1 = 0.7f * s1y + k1 * ai1;
    float2 st = make_float2(h22f(__floats2half2_rn(nr0, ni0)),
                            h22f(__floats2half2_rn(nr1, ni1)));
    ((float2*)nst)[(size_t)cell * (HID / 2) + tid] = st;
    if (las) {
        int c0 = tid << 1;
        float* em = emis + (size_t)(cell & (NCOPY - 1)) * 1024;
        atomicAdd(em + c0,     nr0); atomicAdd(em + 512 + c0,     ni0);
        atomicAdd(em + c0 + 1, nr1); atomicAdd(em + 512 + c0 + 1, ni1);
    }
}

// ---------------------------------------------------------------------------
// Kernel 4: count lasing flags; reduce emission copies; cavity_new;
// cavity_phase (OLD cavity). One block, 512 threads.
__global__ __launch_bounds__(512) void k_cav(const float* __restrict__ emis,
                                             const int* __restrict__ lasv,
                                             const float* __restrict__ cavr,
                                             const float* __restrict__ cavi,
                                             float* __restrict__ cav) {
    __shared__ int cnt[8];
    __shared__ int snl;
    int c = threadIdx.x;
    int wid = c >> 6, lane = c & 63;
    const int4* l4 = (const int4*)lasv;
    int n = 0;
#pragma unroll
    for (int k = 0; k < N_CELLS / 4 / 512; ++k) {  // 8 iters of int4
        int4 v = l4[c + 512 * k];
        n += v.x + v.y + v.z + v.w;
    }
#pragma unroll
    for (int o = 32; o; o >>= 1) n += __shfl_xor(n, o, 64);
    if (lane == 0) cnt[wid] = n;
    __syncthreads();
    if (c == 0) { int t = 0; for (int k = 0; k < 8; ++k) t += cnt[k]; snl = t; }
    __syncthreads();
    int nl = snl;

    float er = 0.f, ei = 0.f;
#pragma unroll 8
    for (int k = 0; k < NCOPY; ++k) {
        er += emis[k * 1024 + c];
        ei += emis[k * 1024 + 512 + c];
    }
    float cr = cavr[c], ci = cavi[c];
    float nr, ni;
    if (nl > 0) {
        float inv = 1.f / (float)(nl > 1 ? nl : 1);
        nr = 0.8f * cr + 0.2f * er * inv;
        ni = 0.8f * ci + 0.2f * ei * inv;
    } else {
        nr = cr;
        ni = ci;
    }
    cav[c] = nr;
    cav[512 + c] = ni;
    cav[1024 + c] = atan2f(ci, cr);                // old cavity phase
}

// ---------------------------------------------------------------------------
// Kernel 5: pred = [cav_new.re, cav_new.im] @ dec_W.T + dec_b. Wave per row.
__global__ __launch_bounds__(512) void k_pred(const float* __restrict__ cav,
                                              const float* __restrict__ dW,
                                              const float* __restrict__ db,
                                              float* __restrict__ out) {
    int gtid = blockIdx.x * 512 + threadIdx.x;
    int j = gtid >> 6;                             // 512 waves -> 512 outputs
    int lane = gtid & 63;
    const float4* w4 = (const float4*)(dW + (size_t)j * (2 * HID));
    const float4* o4 = (const float4*)cav;         // first 1024 floats = out_real
    float acc = 0.f;
#pragma unroll
    for (int t = 0; t < (2 * HID / 4) / 64; ++t) { // 4 iters
        float4 a = w4[lane + 64 * t];
        float4 b = o4[lane + 64 * t];
        acc += a.x * b.x + a.y * b.y + a.z * b.z + a.w * b.w;
    }
#pragma unroll
    for (int o = 32; o; o >>= 1) acc += __shfl_xor(acc, o, 64);
    if (lane == 0) out[j] = acc + db[j];
}

// ---------------------------------------------------------------------------
// Kernel 6: phase-lock lasing cells, add cavity feedback, row-max renorm,
// write per-cell (sum_a, sum_a2) partials. Block per cell. NO global atomics.
__global__ __launch_bounds__(512) void k_fin(const __half2* __restrict__ nst,
                                             const int* __restrict__ lasing,
                                             const float* __restrict__ cav,
                                             float2* __restrict__ vpart) {
    __shared__ float sred[8];
    __shared__ float sbc;
    int cell = blockIdx.x;
    int c = threadIdx.x;
    int wid = c >> 6, lane = c & 63;
    int las = lasing[cell];

    __half2 vh = nst[(size_t)cell * HID + c];
    float vx = __low2float(vh), vy = __high2float(vh);
    if (las) {
        float r = sqrtf(vx * vx + vy * vy);
        float ang = atan2f(vy, vx);
        float locked = 0.3f * cav[1024 + c] + 0.7f * ang;
        float sn, cs;
        __sincosf(locked, &sn, &cs);
        vx = r * cs; vy = r * sn;
    }
    vx += 0.05f * cav[c];
    vy += 0.05f * cav[512 + c];
    float amp = sqrtf(vx * vx + vy * vy);

    // block max
    float m = amp;
#pragma unroll
    for (int o = 32; o; o >>= 1) m = fmaxf(m, __shfl_xor(m, o, 64));
    if (lane == 0) sred[wid] = m;
    __syncthreads();
    if (c == 0) {
        float mm = sred[0];
        for (int k = 1; k < 8; ++k) mm = fmaxf(mm, sred[k]);
        sbc = mm;
    }
    __syncthreads();
    float a = amp / (sbc + 1e-8f);

    // block sums of a and a^2
    float s1 = a, s2 = a * a;
#pragma unroll
    for (int o = 32; o; o >>= 1) { s1 += __shfl_xor(s1, o, 64); s2 += __shfl_xor(s2, o, 64); }
    __shared__ float w1[8], w2[8];
    if (lane == 0) { w1[wid] = s1; w2[wid] = s2; }
    __syncthreads();
    if (c == 0) {
        float t1 = 0.f, t2 = 0.f;
        for (int k = 0; k < 8; ++k) { t1 += w1[k]; t2 += w2[k]; }
        vpart[cell] = make_float2(t1, t2);         // contention-free store
    }
}

// ---------------------------------------------------------------------------
// Kernel 7: reduce per-cell partials (double accum); tension = E[a^2]-E[a]^2
__global__ __launch_bounds__(1024) void k_var(const float2* __restrict__ vpart,
                                              float* __restrict__ out) {
    __shared__ double l1[16], l2[16];
    int c = threadIdx.x;
    int wid = c >> 6, lane = c & 63;
    double s1 = 0.0, s2 = 0.0;
#pragma unroll
    for (int t = 0; t < N_CELLS / 1024; ++t) {     // 16 iters
        float2 p = vpart[c + 1024 * t];
        s1 += (double)p.x;
        s2 += (double)p.y;
    }
#pragma unroll
    for (int o = 32; o; o >>= 1) { s1 += __shfl_xor(s1, o, 64); s2 += __shfl_xor(s2, o, 64); }
    if (lane == 0) { l1[wid] = s1; l2[wid] = s2; }
    __syncthreads();
    if (c == 0) {
        double t1 = 0.0, t2 = 0.0;
        for (int k = 0; k < 16; ++k) { t1 += l1[k]; t2 += l2[k]; }
        double n = (double)N_CELLS * (double)HID;
        double mean = t1 / n;
        out[IND] = (float)(t2 / n - mean * mean);
    }
}

// ---------------------------------------------------------------------------
extern "C" void kernel_launch(void* const* d_in, const int* in_sizes, int n_in,
                              void* d_out, int out_size, void* d_ws, size_t ws_size,
                              hipStream_t stream) {
    const float* x       = (const float*)d_in[0];
    const float* pump_W  = (const float*)d_in[1];
    const float* pump_b  = (const float*)d_in[2];
    const float* dec_W   = (const float*)d_in[3];
    const float* dec_b   = (const float*)d_in[4];
    const float* cs_re   = (const float*)d_in[5];
    const float* cs_im   = (const float*)d_in[6];
    const float* excited = (const float*)d_in[7];
    const float* pvel    = (const float*)d_in[8];
    const float* cav_re  = (const float*)d_in[9];
    const float* cav_im  = (const float*)d_in[10];
    const int*   nbrs    = (const int*)d_in[11];

    float* out = (float*)d_out;
    char* ws = (char*)d_ws;
    float*   emis  = (float*)(ws + EMIS_OFF);
    int*     lasv  = (int*)(ws + LAS_OFF);
    float*   cav   = (float*)(ws + CAV_OFF);
    float2*  vpart = (float2*)(ws + VPART_OFF);
    __half2* rot   = (__half2*)(ws + ROT_OFF);
    __half2* nst   = (__half2*)(ws + NST_OFF);

    k_front<<<ROT_BLOCKS + PUMP_BLOCKS + ZERO_BLOCKS, 256, 0, stream>>>(
        cs_re, cs_im, pvel, rot, x, pump_W, pump_b, excited, lasv, emis);
    k_coup<<<N_CELLS, 256, 0, stream>>>(rot, nbrs, lasv, nst, emis);
    k_cav<<<1, 512, 0, stream>>>(emis, lasv, cav_re, cav_im, cav);
    k_pred<<<64, 512, 0, stream>>>(cav, dec_W, dec_b, out);
    k_fin<<<N_CELLS, 512, 0, stream>>>(nst, lasv, cav, vpart);
    k_var<<<1, 1024, 0, stream>>>(vpart, out);
}